// Round 11
// baseline (84.127 us; speedup 1.0000x reference)
//
#include <hip/hip_runtime.h>

typedef _Float16 half8 __attribute__((ext_vector_type(8)));
typedef float f32x4 __attribute__((ext_vector_type(4)));

#define HH 96
#define WW 96
#define NN (HH * WW)        // 9216
#define T16 (NN / 16)       // 576 16-pixel tiles
#define BLK 512
#define AG (T16 / 8)        // 72 a-groups (8 a-tiles per block, one per wave)
#define NDC 9               // d-chunks: dc covers d = dc*32+1 .. dc*32+32 (+peels)
#define WIN 40              // window tiles: b_local = wave(0..7) + 1 + s(0..31) <= 39
#define NPART (AG * NDC)    // 648 block partials

// Gaussian constants with log2(e) folded in (native v_exp_f32 is exp2):
#define CXY 0.0032059890f
#define CRGB 46.16624131f

// arg_ij as a K=32 f16 MFMA dot (layout verified absmax-0.0 in R7/R8/R9):
//   U = [uh(5), uh(5), ul(5), Aih, Ail, 1, 1, 0..]   (uh/ul = f16 hi/lo split)
//   V = [vh(5), vl(5), vh(5), 1, 1, Ajh, Ajl, 0..]   (v = 2C-scaled values)
// Epilogue: sum w*K = ai*R + (1-2ai)*Q with R=Σw_d K, Q=Σw_d aj K.
// Symmetric coverage: d=0 w=1 (peeled, dc==0); d=1..287 w=2; d=288 w=1 for ALL a
// (each unordered pair hit twice). 576*(1+2*287+1)=576^2.
// No single-address atomics (R4: serialized RMW serializes blocks).
// Two ordinary dispatches — R10 showed hipLaunchCooperativeKernel does NOT
// execute under this harness's graph capture (output never written).

__device__ __forceinline__ void pix_data(
    const float* __restrict__ image, const float* __restrict__ probs, int p,
    float& fy, float& fx, float& r, float& g, float& b, float& A, float& a)
{
    const int y = p / WW;
    fy = (float)y; fx = (float)(p - y * WW);
    r = image[p]; g = image[NN + p]; b = image[2 * NN + p]; a = probs[p];
    A = -CXY * fmaf(fy, fy, fx * fx) - CRGB * fmaf(r, r, fmaf(g, g, b * b));
}

struct Frag { union { uint4 q; half8 h; }; };

__device__ __forceinline__ void step(
    const uint4* __restrict__ sv, const float* __restrict__ sa,
    int bl, int quad, int col, const half8& Av, f32x4& R, f32x4& Q)
{
    Frag B;
    B.q = sv[bl * 64 + quad * 16 + col];
    f32x4 c0 = {0.0f, 0.0f, 0.0f, 0.0f};
    const f32x4 dd = __builtin_amdgcn_mfma_f32_16x16x32_f16(Av, B.h, c0, 0, 0, 0);
    const float aj = sa[bl * 16 + col];
#pragma unroll
    for (int r2 = 0; r2 < 4; ++r2) {
        const float K = __builtin_amdgcn_exp2f(dd[r2]);
        R[r2] += K;
        Q[r2] = fmaf(aj, K, Q[r2]);
    }
}

__global__ __launch_bounds__(BLK, 6) void crf_mfma5(
    const float* __restrict__ probs, const float* __restrict__ image,
    float* __restrict__ partials)
{
    __shared__ uint4 sv[WIN * 64];   // 40 KB: V fragments for the window
    __shared__ float sa[WIN * 16];   // aj for the window
    __shared__ float wsum[8];

    const int g = blockIdx.x, dc = blockIdx.y;
    const int tid = threadIdx.x, lane = tid & 63, wave = tid >> 6;
    const int quad = lane >> 4, col = lane & 15;
    const int wb = g * 8 + dc * 32;   // window base tile (mod T16)

    // ---- Stage window: compute V fragments straight into LDS. ----
    for (int t = tid; t < WIN * 16; t += BLK) {
        int tile = wb + (t >> 4); if (tile >= T16) tile -= T16;
        const int j = tile * 16 + (t & 15);
        float fy, fx, r, gg, b, Aj, aj;
        pix_data(image, probs, j, fy, fx, r, gg, b, Aj, aj);
        const float vv[5] = {2.0f * CXY * fy, 2.0f * CXY * fx,
                             2.0f * CRGB * r, 2.0f * CRGB * gg, 2.0f * CRGB * b};
        union { _Float16 h[32]; uint4 q[4]; } V;
#pragma unroll
        for (int k = 0; k < 32; ++k) V.h[k] = (_Float16)0.0f;
#pragma unroll
        for (int d = 0; d < 5; ++d) {
            const _Float16 vh = (_Float16)vv[d];
            const _Float16 vl = (_Float16)(vv[d] - (float)vh);
            V.h[d] = vh; V.h[5 + d] = vl; V.h[10 + d] = vh;
        }
        const _Float16 Ah = (_Float16)Aj, Al = (_Float16)(Aj - (float)Ah);
        V.h[15] = (_Float16)1.0f; V.h[16] = (_Float16)1.0f; V.h[17] = Ah; V.h[18] = Al;
#pragma unroll
        for (int q = 0; q < 4; ++q) sv[(t >> 4) * 64 + q * 16 + (t & 15)] = V.q[q];
        sa[t] = aj;
    }

    // ---- Per-wave prologue (register-only, overlaps staging): A fragment. ----
    const int a_tile = g * 8 + wave;          // < 576 always
    const int ip = a_tile * 16 + col;
    float fy, fx, r, gg, b, Ai, dum;
    pix_data(image, probs, ip, fy, fx, r, gg, b, Ai, dum);
    Frag A;
#pragma unroll
    for (int k = 0; k < 4; ++k) ((unsigned*)&A.q)[k] = 0u;
    {
        _Float16* Ah8 = (_Float16*)&A.q;
        const float uv[5] = {fy, fx, r, gg, b};
        _Float16 uh[5], ul[5];
#pragma unroll
        for (int d = 0; d < 5; ++d) {
            uh[d] = (_Float16)uv[d];
            ul[d] = (_Float16)(uv[d] - (float)uh[d]);
        }
        const _Float16 Aih = (_Float16)Ai, Ail = (_Float16)(Ai - (float)Aih);
        if (quad == 0) {
            Ah8[0] = uh[0]; Ah8[1] = uh[1]; Ah8[2] = uh[2]; Ah8[3] = uh[3];
            Ah8[4] = uh[4]; Ah8[5] = uh[0]; Ah8[6] = uh[1]; Ah8[7] = uh[2];
        } else if (quad == 1) {
            Ah8[0] = uh[3]; Ah8[1] = uh[4]; Ah8[2] = ul[0]; Ah8[3] = ul[1];
            Ah8[4] = ul[2]; Ah8[5] = ul[3]; Ah8[6] = ul[4]; Ah8[7] = Aih;
        } else if (quad == 2) {
            Ah8[0] = Ail; Ah8[1] = (_Float16)1.0f; Ah8[2] = (_Float16)1.0f;
        } // quad 3: all zero
    }
    // Epilogue row data: rows r2 -> i = a_tile*16 + quad*4 + r2 (verified C/D map).
    const float4 aiv = *(const float4*)(probs + a_tile * 16 + quad * 4);
    const float air[4] = {aiv.x, aiv.y, aiv.z, aiv.w};

    f32x4 R2 = {0.0f, 0.0f, 0.0f, 0.0f}, Q2 = {0.0f, 0.0f, 0.0f, 0.0f};  // w=2
    f32x4 R1 = {0.0f, 0.0f, 0.0f, 0.0f}, Q1 = {0.0f, 0.0f, 0.0f, 0.0f};  // w=1
    __syncthreads();

    // Fixed trip counts: sv/sa offsets fold to immediates off one base.
    if (dc != NDC - 1) {
#pragma unroll 8
        for (int s = 0; s < 32; ++s)
            step(sv, sa, wave + 1 + s, quad, col, A.h, R2, Q2);
    } else {
#pragma unroll 8
        for (int s = 0; s < 31; ++s)
            step(sv, sa, wave + 1 + s, quad, col, A.h, R2, Q2);
    }
    // Peeled weight-1 iterations (block-uniform branches).
    if (dc == 0)        step(sv, sa, wave,      quad, col, A.h, R1, Q1);  // d=0 diag
    if (dc == NDC - 1)  step(sv, sa, wave + 32, quad, col, A.h, R1, Q1);  // d=288

    // Apply per-row factors: sum w*K*(ai + aj*(1-2ai)) = ai*R + (1-2ai)*Q.
    float s4 = 0.0f;
#pragma unroll
    for (int r2 = 0; r2 < 4; ++r2) {
        const float Rt = fmaf(2.0f, R2[r2], R1[r2]);
        const float Qt = fmaf(2.0f, Q2[r2], Q1[r2]);
        const float ci = fmaf(-2.0f, air[r2], 1.0f);
        s4 += fmaf(air[r2], Rt, ci * Qt);
    }
    for (int off = 32; off > 0; off >>= 1)
        s4 += __shfl_down(s4, off, 64);
    if (lane == 0) wsum[wave] = s4;
    __syncthreads();
    if (tid == 0) {
        float bs = 0.0f;
#pragma unroll
        for (int w = 0; w < 8; ++w) bs += wsum[w];
        partials[dc * AG + g] = bs;
    }
}

__global__ __launch_bounds__(256) void crf_finalize_kernel(
    const float* __restrict__ partials, float* __restrict__ out)
{
    const int tid = threadIdx.x;
    float s = 0.0f;
    for (int t = tid; t < NPART; t += 256)
        s += partials[t];
    for (int off = 32; off > 0; off >>= 1)
        s += __shfl_down(s, off, 64);
    __shared__ float wsum[4];
    if ((tid & 63) == 0) wsum[tid >> 6] = s;
    __syncthreads();
    if (tid == 0)
        out[0] = ((wsum[0] + wsum[1]) + (wsum[2] + wsum[3])) * (1.0f / (float)NN);
}

extern "C" void kernel_launch(void* const* d_in, const int* in_sizes, int n_in,
                              void* d_out, int out_size, void* d_ws, size_t ws_size,
                              hipStream_t stream) {
    const float* probs = (const float*)d_in[0];  // [1,2,96,96] fp32
    const float* image = (const float*)d_in[1];  // [1,3,96,96] fp32
    float* out = (float*)d_out;                  // [1] fp32
    float* partials = (float*)d_ws;              // NPART floats

    crf_mfma5<<<dim3(AG, NDC), dim3(BLK), 0, stream>>>(probs, image, partials);
    crf_finalize_kernel<<<dim3(1), dim3(256), 0, stream>>>(partials, out);
}

// Round 12
// 64.842 us; speedup vs baseline: 1.2974x; 1.2974x over previous
//
#include <hip/hip_runtime.h>

typedef _Float16 half8 __attribute__((ext_vector_type(8)));
typedef float f32x4 __attribute__((ext_vector_type(4)));

#define HH 96
#define WW 96
#define NN (HH * WW)        // 9216
#define T16 (NN / 16)       // 576 16-pixel tiles
#define BLK 512
#define AG (T16 / 8)        // 72 a-groups (8 a-tiles per block, one per wave)
#define NDC 9               // d-chunks: dc covers d = dc*32+1 .. dc*32+32 (+peels)
#define WIN 40              // window tiles: b_local = wave(0..7) + 1 + s(0..31) <= 39
#define NPART (AG * NDC)    // 648 block partials

// Gaussian constants with log2(e) folded in (native v_exp_f32 is exp2):
#define CXY 0.0032059890f
#define CRGB 46.16624131f

// arg_ij as a K=32 f16 MFMA dot (layout verified absmax-0.0 R7/R8/R9):
//   U = [uh(5), uh(5), ul(5), Aih, Ail, 1, 1, 0..]   (uh/ul = f16 hi/lo split)
//   V = [vh(5), vl(5), vh(5), 1, 1, Ajh, Ajl, 0..]   (v = 2C-scaled values)
// Epilogue: sum w*K = ai*R + (1-2ai)*Q with R=Σ K, Q=Σ aj K.
// Symmetric coverage: d=0 w=1 (peeled, dc==0); d=1..287 w=2; d=288 w=1 for ALL a
// (each unordered pair hit twice). 576*(1+2*287+1)=576^2.
// HYGIENE (R11 lesson): A-fragment must be built branchlessly in a half8
// vector — union writes through casted pointers / divergent branches demote
// it to scratch (R11: VGPR 40, FETCH 9.5 MB, 44 µs, VALUBusy 11%).
// No single-address atomics (R4). No cooperative launch (R10: never executes).

__device__ __forceinline__ void pix_data(
    const float* __restrict__ image, const float* __restrict__ probs, int p,
    float& fy, float& fx, float& r, float& g, float& b, float& A, float& a)
{
    const int y = p / WW;
    fy = (float)y; fx = (float)(p - y * WW);
    r = image[p]; g = image[NN + p]; b = image[2 * NN + p]; a = probs[p];
    A = -CXY * fmaf(fy, fy, fx * fx) - CRGB * fmaf(r, r, fmaf(g, g, b * b));
}

__global__ __launch_bounds__(BLK, 6) void crf_mfma6(
    const float* __restrict__ probs, const float* __restrict__ image,
    float* __restrict__ partials)
{
    __shared__ uint4 sv[WIN * 64];   // 40 KB: V fragments for the window
    __shared__ float sa[WIN * 16];   // aj for the window
    __shared__ float wsum[8];

    const int g = blockIdx.x, dc = blockIdx.y;
    const int tid = threadIdx.x, lane = tid & 63, wave = tid >> 6;
    const int quad = lane >> 4, col = lane & 15;
    const int wb = g * 8 + dc * 32;   // window base tile (mod T16)

    // ---- Stage window: compute V fragments straight into LDS. ----
    for (int t = tid; t < WIN * 16; t += BLK) {
        int tile = wb + (t >> 4); if (tile >= T16) tile -= T16;
        const int j = tile * 16 + (t & 15);
        float fy, fx, r, gg, b, Aj, aj;
        pix_data(image, probs, j, fy, fx, r, gg, b, Aj, aj);
        const float vv[5] = {2.0f * CXY * fy, 2.0f * CXY * fx,
                             2.0f * CRGB * r, 2.0f * CRGB * gg, 2.0f * CRGB * b};
        union { _Float16 h[32]; uint4 q[4]; } V;
#pragma unroll
        for (int k = 0; k < 32; ++k) V.h[k] = (_Float16)0.0f;
#pragma unroll
        for (int d = 0; d < 5; ++d) {
            const _Float16 vh = (_Float16)vv[d];
            const _Float16 vl = (_Float16)(vv[d] - (float)vh);
            V.h[d] = vh; V.h[5 + d] = vl; V.h[10 + d] = vh;
        }
        const _Float16 Ah = (_Float16)Aj, Al = (_Float16)(Aj - (float)Ah);
        V.h[15] = (_Float16)1.0f; V.h[16] = (_Float16)1.0f; V.h[17] = Ah; V.h[18] = Al;
#pragma unroll
        for (int q = 0; q < 4; ++q) sv[(t >> 4) * 64 + q * 16 + (t & 15)] = V.q[q];
        sa[t] = aj;
    }

    // ---- Per-wave prologue: A fragment, branchless (register-guaranteed). ----
    const int a_tile = g * 8 + wave;          // < 576 always
    const int ip = a_tile * 16 + col;
    float fy, fx, r, gg, b, Ai, dum;
    pix_data(image, probs, ip, fy, fx, r, gg, b, Ai, dum);
    half8 Av;
    {
        const float uv[5] = {fy, fx, r, gg, b};
        _Float16 uh[5], ul[5];
#pragma unroll
        for (int d = 0; d < 5; ++d) {
            uh[d] = (_Float16)uv[d];
            ul[d] = (_Float16)(uv[d] - (float)uh[d]);
        }
        const _Float16 Aih = (_Float16)Ai, Ail = (_Float16)(Ai - (float)Aih);
        const _Float16 z = (_Float16)0.0f, one = (_Float16)1.0f;
        // A[j] = U[quad*8 + j]; U per comment above. Ternaries -> v_cndmask.
        Av[0] = quad == 0 ? uh[0] : quad == 1 ? uh[3] : quad == 2 ? Ail : z;
        Av[1] = quad == 0 ? uh[1] : quad == 1 ? uh[4] : quad == 2 ? one : z;
        Av[2] = quad == 0 ? uh[2] : quad == 1 ? ul[0] : quad == 2 ? one : z;
        Av[3] = quad == 0 ? uh[3] : quad == 1 ? ul[1] : z;
        Av[4] = quad == 0 ? uh[4] : quad == 1 ? ul[2] : z;
        Av[5] = quad == 0 ? uh[0] : quad == 1 ? ul[3] : z;
        Av[6] = quad == 0 ? uh[1] : quad == 1 ? ul[4] : z;
        Av[7] = quad == 0 ? uh[2] : quad == 1 ? Aih : z;
    }
    // Epilogue row data: rows r2 -> i = a_tile*16 + quad*4 + r2 (verified C/D map).
    const float4 aiv = *(const float4*)(probs + a_tile * 16 + quad * 4);
    const float air[4] = {aiv.x, aiv.y, aiv.z, aiv.w};

    f32x4 R2 = {0.0f, 0.0f, 0.0f, 0.0f}, Q2 = {0.0f, 0.0f, 0.0f, 0.0f};  // w=2
    f32x4 R1 = {0.0f, 0.0f, 0.0f, 0.0f}, Q1 = {0.0f, 0.0f, 0.0f, 0.0f};  // w=1
    __syncthreads();

    const int nmain = (dc == NDC - 1) ? 31 : 32;   // dc=8 peels d=288
#pragma unroll 2
    for (int s = 0; s < nmain; ++s) {
        const int bl = wave + 1 + s;              // 1..39
        union { uint4 q; half8 h; } B;
        B.q = sv[bl * 64 + quad * 16 + col];
        f32x4 c0 = {0.0f, 0.0f, 0.0f, 0.0f};
        const f32x4 dd = __builtin_amdgcn_mfma_f32_16x16x32_f16(Av, B.h, c0, 0, 0, 0);
        const float aj = sa[bl * 16 + col];
#pragma unroll
        for (int r2 = 0; r2 < 4; ++r2) {
            const float K = __builtin_amdgcn_exp2f(dd[r2]);
            R2[r2] += K;
            Q2[r2] = fmaf(aj, K, Q2[r2]);
        }
    }
    // Peeled weight-1 iterations (block-uniform branches).
    if (dc == NDC - 1 || dc == 0) {
        const int bl = (dc == 0) ? wave : wave + 32;   // d=0 diag / d=288
        union { uint4 q; half8 h; } B;
        B.q = sv[bl * 64 + quad * 16 + col];
        f32x4 c0 = {0.0f, 0.0f, 0.0f, 0.0f};
        const f32x4 dd = __builtin_amdgcn_mfma_f32_16x16x32_f16(Av, B.h, c0, 0, 0, 0);
        const float aj = sa[bl * 16 + col];
#pragma unroll
        for (int r2 = 0; r2 < 4; ++r2) {
            const float K = __builtin_amdgcn_exp2f(dd[r2]);
            R1[r2] += K;
            Q1[r2] = fmaf(aj, K, Q1[r2]);
        }
    }

    // Apply per-row factors: sum w*K*(ai + aj*(1-2ai)) = ai*R + (1-2ai)*Q.
    float s4 = 0.0f;
#pragma unroll
    for (int r2 = 0; r2 < 4; ++r2) {
        const float Rt = fmaf(2.0f, R2[r2], R1[r2]);
        const float Qt = fmaf(2.0f, Q2[r2], Q1[r2]);
        const float ci = fmaf(-2.0f, air[r2], 1.0f);
        s4 += fmaf(air[r2], Rt, ci * Qt);
    }
    for (int off = 32; off > 0; off >>= 1)
        s4 += __shfl_down(s4, off, 64);
    if (lane == 0) wsum[wave] = s4;
    __syncthreads();
    if (tid == 0) {
        float bs = 0.0f;
#pragma unroll
        for (int w = 0; w < 8; ++w) bs += wsum[w];
        partials[dc * AG + g] = bs;
    }
}

__global__ __launch_bounds__(256) void crf_finalize_kernel(
    const float* __restrict__ partials, float* __restrict__ out)
{
    const int tid = threadIdx.x;
    float s = 0.0f;
    for (int t = tid; t < NPART; t += 256)
        s += partials[t];
    for (int off = 32; off > 0; off >>= 1)
        s += __shfl_down(s, off, 64);
    __shared__ float wsum[4];
    if ((tid & 63) == 0) wsum[tid >> 6] = s;
    __syncthreads();
    if (tid == 0)
        out[0] = ((wsum[0] + wsum[1]) + (wsum[2] + wsum[3])) * (1.0f / (float)NN);
}

extern "C" void kernel_launch(void* const* d_in, const int* in_sizes, int n_in,
                              void* d_out, int out_size, void* d_ws, size_t ws_size,
                              hipStream_t stream) {
    const float* probs = (const float*)d_in[0];  // [1,2,96,96] fp32
    const float* image = (const float*)d_in[1];  // [1,3,96,96] fp32
    float* out = (float*)d_out;                  // [1] fp32
    float* partials = (float*)d_ws;              // NPART floats

    crf_mfma6<<<dim3(AG, NDC), dim3(BLK), 0, stream>>>(probs, image, partials);
    crf_finalize_kernel<<<dim3(1), dim3(256), 0, stream>>>(partials, out);
}